// Round 1
// baseline (1722.286 us; speedup 1.0000x reference)
//
#include <hip/hip_runtime.h>

#define NB 256
#define NI 1000
#define ND 800
#define NH1 256
#define NH2 16
#define NPH 256

typedef __attribute__((ext_vector_type(8))) short short8;
typedef __attribute__((ext_vector_type(4))) float f32x4;

__device__ inline unsigned short f2bf(float f) {
    union { __bf16 b; unsigned short u; } c; c.b = (__bf16)f; return c.u;
}
__device__ inline float bf2f(unsigned short u) {
    union { unsigned short u; __bf16 b; } c; c.u = u; return (float)c.b;
}

// ---------------------------------------------------------------- prep ----
__global__ void prep_kernel(const float* __restrict__ W1, const float* __restrict__ W2,
                            const float* __restrict__ Wp,
                            unsigned short* __restrict__ W1bf,
                            unsigned short* __restrict__ W2bf,
                            unsigned short* __restrict__ WpT) {
    int idx = blockIdx.x * blockDim.x + threadIdx.x;
    int stride = gridDim.x * blockDim.x;
    for (int i = idx; i < NH1 * ND; i += stride) W1bf[i] = f2bf(W1[i]);
    for (int i = idx; i < NH2 * NH1; i += stride) W2bf[i] = f2bf(W2[i]);
    for (int i = idx; i < NPH * NI; i += stride) {
        int h = i / NI, k = i - h * NI;
        WpT[k * NPH + h] = f2bf(Wp[i]);
    }
}

// ------------------------------------------------------------- sections ----
// Per block: b = blockIdx.y, i-tile of 64 = blockIdx.x. Computes
// fc[b, i0..i0+63] = W3 . relu(W2 . relu(W1 . x + b1) + b2) + b3
__global__ __launch_bounds__(256, 3)
void sec_kernel(const float* __restrict__ state, const unsigned short* __restrict__ W1bf,
                const float* __restrict__ b1, const unsigned short* __restrict__ W2bf,
                const float* __restrict__ b2, const float* __restrict__ W3,
                const float* __restrict__ b3, float* __restrict__ fc) {
    // LDS: A [64 i][32 d] bf16, chunk-XOR-swizzled (4 KB)
    //      B [256 h][32 d] bf16, chunk-XOR-swizzled (16 KB)
    //      H1 [64 i][264] bf16 padded (33 KB)   -> total 54,272 B = 3 blocks/CU
    __shared__ unsigned short Asm[64 * 32];
    __shared__ unsigned short Bsm[256 * 32];
    __shared__ unsigned short H1sm[64 * 264];

    const int tid = threadIdx.x;
    const int w = tid >> 6, l = tid & 63;
    const int lm = l & 15, lq = l >> 4;
    const int i0 = blockIdx.x * 64;
    const int b  = blockIdx.y;

    f32x4 acc[4][4];
#pragma unroll
    for (int mt = 0; mt < 4; mt++)
#pragma unroll
        for (int nt = 0; nt < 4; nt++) acc[mt][nt] = (f32x4){0.f, 0.f, 0.f, 0.f};

    // A staging: thread = (row iL = l, d-chunk dg = w). 8 coalesced scalar loads,
    // cvt to bf16, one ds_write_b128 at swizzled chunk position.
    const bool valid = (i0 + l) < NI;
    const float* sp = state + ((size_t)b * ND + (size_t)w * 8) * NI + (i0 + l);
    unsigned short* aw = Asm + l * 32 + ((w ^ (l & 3)) * 8);
    const int ksw = ((lq ^ (l & 3)) * 8);   // swizzled chunk offset for fragment reads

    for (int k0 = 0; k0 < ND; k0 += 32) {
        __syncthreads();
        // --- B tile: global_load_lds 16B, source-address XOR swizzle ---
#pragma unroll
        for (int q = 0; q < 4; q++) {
            int h = q * 64 + w * 16 + (l >> 2);
            int cs = (l & 3) ^ ((l >> 2) & 3);
            const unsigned short* g = W1bf + h * ND + k0 + cs * 8;
            unsigned short* lp = Bsm + (q * 64 + w * 16) * 32 + l * 8;
            __builtin_amdgcn_global_load_lds(
                (const __attribute__((address_space(1))) void*)g,
                (__attribute__((address_space(3))) void*)lp, 16, 0, 0);
        }
        // --- A tile: fp32 loads -> bf16 -> LDS ---
        const float* spk = sp + (size_t)k0 * NI;
        float v[8];
#pragma unroll
        for (int jj = 0; jj < 8; jj++) v[jj] = valid ? spk[(size_t)jj * NI] : 0.f;
        union { short8 v8; unsigned short us[8]; } pk;
#pragma unroll
        for (int jj = 0; jj < 8; jj++) pk.us[jj] = f2bf(v[jj]);
        *(short8*)aw = pk.v8;
        __syncthreads();
        // --- fragments + MFMA ---
        short8 af[4], bf[4];
#pragma unroll
        for (int mt = 0; mt < 4; mt++)
            af[mt] = *(const short8*)(Asm + (mt * 16 + lm) * 32 + ksw);
#pragma unroll
        for (int nt = 0; nt < 4; nt++)
            bf[nt] = *(const short8*)(Bsm + (w * 64 + nt * 16 + lm) * 32 + ksw);
#pragma unroll
        for (int mt = 0; mt < 4; mt++)
#pragma unroll
            for (int nt = 0; nt < 4; nt++)
                acc[mt][nt] = __builtin_amdgcn_mfma_f32_16x16x32_bf16(
                    af[mt], bf[nt], acc[mt][nt], 0, 0, 0);
    }

    // --- epilogue 1: bias + relu -> h1 (bf16) in LDS ---
#pragma unroll
    for (int nt = 0; nt < 4; nt++) {
        int col = w * 64 + nt * 16 + lm;
        float bias = b1[col];
#pragma unroll
        for (int mt = 0; mt < 4; mt++) {
            f32x4 a = acc[mt][nt];
#pragma unroll
            for (int r = 0; r < 4; r++) {
                float hv = fmaxf(a[r] + bias, 0.f);
                int row = mt * 16 + lq * 4 + r;
                H1sm[row * 264 + col] = f2bf(hv);
            }
        }
    }
    __syncthreads();

    // --- layer 2: wave w does rows w*16..w*16+15; K=256 via 8 MFMAs ---
    f32x4 acc2 = (f32x4){0.f, 0.f, 0.f, 0.f};
#pragma unroll
    for (int kk = 0; kk < 8; kk++) {
        int kb = kk * 32 + lq * 8;
        short8 a2 = *(const short8*)(H1sm + (w * 16 + lm) * 264 + kb);
        short8 b2f = *(const short8*)(W2bf + lm * NH1 + kb);   // W2[g=lm][h=kb..kb+7]
        acc2 = __builtin_amdgcn_mfma_f32_16x16x32_bf16(a2, b2f, acc2, 0, 0, 0);
    }
    // h2 = relu(acc2 + b2[g]); sec = sum_g h2*W3[g] + b3  (16-lane reduce)
    float b2v = b2[lm];
    float w3v = W3[lm];
    float p[4];
#pragma unroll
    for (int r = 0; r < 4; r++) p[r] = fmaxf(acc2[r] + b2v, 0.f) * w3v;
#pragma unroll
    for (int m = 1; m < 16; m <<= 1)
#pragma unroll
        for (int r = 0; r < 4; r++) p[r] += __shfl_xor(p[r], m);
    if (lm == 0) {
        float b3v = b3[0];
#pragma unroll
        for (int r = 0; r < 4; r++) {
            int gi = i0 + w * 16 + lq * 4 + r;
            if (gi < NI) fc[b * NI + gi] = p[r] + b3v;
        }
    }
}

// ----------------------------------------------------------------- head ----
// One block per b: y = relu(fc_row @ WpT + bp); out[b] = y . Wv + bv
__global__ __launch_bounds__(256)
void head_kernel(const float* __restrict__ fc, const unsigned short* __restrict__ WpT,
                 const float* __restrict__ bp, const float* __restrict__ Wv,
                 const float* __restrict__ bv, float* __restrict__ out) {
    __shared__ float fcs[NI];
    __shared__ float psum[4][NPH];
    __shared__ float red[4];
    const int tid = threadIdx.x;
    const int b = blockIdx.x;
    for (int k = tid; k < NI; k += 256) fcs[k] = fc[b * NI + k];
    __syncthreads();

    const int hq = tid & 63;    // h = hq*4 + c
    const int kq = tid >> 6;    // k-range [kq*250, kq*250+250)
    float a0 = 0, a1 = 0, a2 = 0, a3 = 0;
    const unsigned short* wp = WpT + hq * 4;
    const int kb = kq * 250;
    for (int k = kb; k < kb + 250; k++) {
        float f = fcs[k];
        ushort4 r4 = *(const ushort4*)(wp + k * NPH);
        a0 = fmaf(f, bf2f(r4.x), a0);
        a1 = fmaf(f, bf2f(r4.y), a1);
        a2 = fmaf(f, bf2f(r4.z), a2);
        a3 = fmaf(f, bf2f(r4.w), a3);
    }
    psum[kq][hq * 4 + 0] = a0;
    psum[kq][hq * 4 + 1] = a1;
    psum[kq][hq * 4 + 2] = a2;
    psum[kq][hq * 4 + 3] = a3;
    __syncthreads();

    float y = psum[0][tid] + psum[1][tid] + psum[2][tid] + psum[3][tid] + bp[tid];
    y = fmaxf(y, 0.f);
    float pv = y * Wv[tid];
#pragma unroll
    for (int m = 1; m < 64; m <<= 1) pv += __shfl_xor(pv, m);
    if ((tid & 63) == 0) red[tid >> 6] = pv;
    __syncthreads();
    if (tid == 0) out[b] = red[0] + red[1] + red[2] + red[3] + bv[0];
}

// --------------------------------------------------------------- launch ----
extern "C" void kernel_launch(void* const* d_in, const int* in_sizes, int n_in,
                              void* d_out, int out_size, void* d_ws, size_t ws_size,
                              hipStream_t stream) {
    const float* state = (const float*)d_in[0];
    const float* W1 = (const float*)d_in[1];
    const float* b1 = (const float*)d_in[2];
    const float* W2 = (const float*)d_in[3];
    const float* b2 = (const float*)d_in[4];
    const float* W3 = (const float*)d_in[5];
    const float* b3 = (const float*)d_in[6];
    const float* Wp = (const float*)d_in[7];
    const float* bp = (const float*)d_in[8];
    const float* Wv = (const float*)d_in[9];
    const float* bv = (const float*)d_in[10];
    float* out = (float*)d_out;

    char* ws = (char*)d_ws;
    unsigned short* W1bf = (unsigned short*)ws;              // 409,600 B
    unsigned short* W2bf = (unsigned short*)(ws + 409600);   //   8,192 B
    unsigned short* WpT  = (unsigned short*)(ws + 417792);   // 512,000 B
    float*          fc   = (float*)(ws + 929792);            // 1,024,000 B

    prep_kernel<<<464, 256, 0, stream>>>(W1, W2, Wp, W1bf, W2bf, WpT);
    sec_kernel<<<dim3(16, 256), 256, 0, stream>>>(state, W1bf, b1, W2bf, b2, W3, b3, fc);
    head_kernel<<<NB, 256, 0, stream>>>(fc, WpT, bp, Wv, bv, out);
}

// Round 2
// 1171.300 us; speedup vs baseline: 1.4704x; 1.4704x over previous
//
#include <hip/hip_runtime.h>

#define NB 256
#define NI 1000
#define ND 800
#define NH1 256
#define NH2 16
#define NPH 256
#define NIP 1024   // padded interval count (zero-padded tail)

typedef __attribute__((ext_vector_type(8))) short short8;
typedef __attribute__((ext_vector_type(4))) float f32x4;

__device__ inline unsigned short f2bf(float f) {
    union { __bf16 b; unsigned short u; } c; c.b = (__bf16)f; return c.u;
}
__device__ inline float bf2f(unsigned short u) {
    union { unsigned short u; __bf16 b; } c; c.u = u; return (float)c.b;
}

// Raw barrier: waits only for our own LDS ops, leaves global loads in flight
// (HIP __syncthreads would emit s_waitcnt vmcnt(0) and kill the pipeline).
__device__ inline void barrier_lds() {
    asm volatile("s_waitcnt lgkmcnt(0)\n\ts_barrier" ::: "memory");
}

// ---------------------------------------------------------------- prep ----
// Casts W1,W2 to bf16; zeroes fc's padded tail (ws is re-poisoned 0xAA each call).
__global__ void prep_kernel(const float* __restrict__ W1, const float* __restrict__ W2,
                            unsigned short* __restrict__ W1bf,
                            unsigned short* __restrict__ W2bf,
                            unsigned short* __restrict__ fc) {
    int idx = blockIdx.x * blockDim.x + threadIdx.x;
    int stride = gridDim.x * blockDim.x;
    for (int i = idx; i < NH1 * ND; i += stride) W1bf[i] = f2bf(W1[i]);
    for (int i = idx; i < NH2 * NH1; i += stride) W2bf[i] = f2bf(W2[i]);
    for (int i = idx; i < NB * (NIP - NI); i += stride) {
        int b = i / (NIP - NI), c = i - b * (NIP - NI);
        fc[b * NIP + NI + c] = 0;  // bf16 zero
    }
}

// ----------------------------------------------------- Wp transpose ----
// Wp [256 h][1000 k] fp32 -> WpT [1024 k][256 h] bf16, zero-padded k>=1000.
// Coalesced read + coalesced write via padded LDS tile.
__global__ __launch_bounds__(256)
void wpt_kernel(const float* __restrict__ Wp, unsigned short* __restrict__ WpT) {
    __shared__ float tile[64][65];
    const int kt = blockIdx.x;            // 16 k-tiles of 64 (covers 1024)
    const int ht = blockIdx.y;            // 4 h-tiles of 64
    const int lk = threadIdx.x & 63;
    const int lh = threadIdx.x >> 6;      // 0..3
#pragma unroll
    for (int rr = 0; rr < 16; rr++) {
        int h = ht * 64 + lh * 16 + rr;
        int k = kt * 64 + lk;
        tile[lh * 16 + rr][lk] = (k < NI) ? Wp[h * NI + k] : 0.f;
    }
    __syncthreads();
#pragma unroll
    for (int rr = 0; rr < 16; rr++) {
        int kr = lh * 16 + rr;
        WpT[(kt * 64 + kr) * NPH + ht * 64 + lk] = f2bf(tile[lk][kr]);
    }
}

// ------------------------------------------------------------- sections ----
// Block: b = blockIdx.y, 64-interval tile = blockIdx.x.
// Pipelined: A (state) 3-deep register prefetch -> bf16 -> double-buffered LDS;
// B (W1bf) fragments loaded straight from global (L2-hot), 1-iter prefetch;
// raw barriers so prefetch loads stay in flight across iterations.
__global__ __launch_bounds__(256, 3)
void sec_kernel(const float* __restrict__ state, const unsigned short* __restrict__ W1bf,
                const float* __restrict__ b1, const unsigned short* __restrict__ W2bf,
                const float* __restrict__ b2, const float* __restrict__ W3,
                const float* __restrict__ b3, unsigned short* __restrict__ fc) {
    __shared__ union {
        unsigned short A[2][64 * 32];     // double-buffered A tile (2 x 4 KB)
        unsigned short H1[64 * 264];      // epilogue h1 tile (33 KB), overlaid
    } sm;

    const int tid = threadIdx.x;
    const int w = tid >> 6, l = tid & 63;
    const int lm = l & 15, lq = l >> 4;
    const int i0 = blockIdx.x * 64;
    const int b  = blockIdx.y;

    f32x4 acc[4][4];
#pragma unroll
    for (int mt = 0; mt < 4; mt++)
#pragma unroll
        for (int nt = 0; nt < 4; nt++) acc[mt][nt] = (f32x4){0.f, 0.f, 0.f, 0.f};

    // A staging role: thread = (i-row l, d-chunk w). Clamp OOB i to row 999;
    // garbage columns are never written out (gi<NI guard at the end).
    const int il = (i0 + l < NI) ? (i0 + l) : (NI - 1);
    const float* sp = state + ((size_t)b * ND + (size_t)w * 8) * NI + il;
    unsigned short* aw0 = sm.A[0] + l * 32 + ((w ^ (l & 3)) * 8);
    unsigned short* aw1 = sm.A[1] + l * 32 + ((w ^ (l & 3)) * 8);
    const int ksw = (lq ^ (l & 3)) * 8;   // XOR-swizzled chunk for fragment reads
    const unsigned short* gb0 = W1bf + (w * 64 + lm) * ND + lq * 8;

    float aR[3][8];
    short8 bR[2][4];

    // --- preamble: issue A[0..2] and B[0]; stage A[0] into LDS ---
#pragma unroll
    for (int s = 0; s < 3; s++) {
        const float* p = sp + (size_t)(s * 32) * NI;
#pragma unroll
        for (int jj = 0; jj < 8; jj++) aR[s][jj] = p[(size_t)jj * NI];
    }
#pragma unroll
    for (int nt = 0; nt < 4; nt++)
        bR[0][nt] = *(const short8*)(gb0 + nt * 16 * ND);
    {
        union { short8 v8; unsigned short us[8]; } pk;
#pragma unroll
        for (int jj = 0; jj < 8; jj++) pk.us[jj] = f2bf(aR[0][jj]);
        *(short8*)aw0 = pk.v8;
    }
    barrier_lds();

#pragma unroll
    for (int k = 0; k < 25; k++) {
        const int cur = k & 1;
        // 1. prefetch A[k+3] into the slot A[k] just vacated
        if (k + 3 < 25) {
            const float* p = sp + (size_t)((k + 3) * 32) * NI;
#pragma unroll
            for (int jj = 0; jj < 8; jj++) aR[k % 3][jj] = p[(size_t)jj * NI];
        }
        // 2. prefetch B[k+1] fragments (L2-hot W1bf, coalesced dwordx4)
        if (k + 1 < 25) {
            const unsigned short* gb = gb0 + (k + 1) * 32;
#pragma unroll
            for (int nt = 0; nt < 4; nt++)
                bR[(k + 1) & 1][nt] = *(const short8*)(gb + nt * 16 * ND);
        }
        // 3. A fragments from LDS + MFMA
        {
            const unsigned short* ab = cur ? sm.A[1] : sm.A[0];
            short8 af[4];
#pragma unroll
            for (int mt = 0; mt < 4; mt++)
                af[mt] = *(const short8*)(ab + (mt * 16 + lm) * 32 + ksw);
#pragma unroll
            for (int mt = 0; mt < 4; mt++)
#pragma unroll
                for (int nt = 0; nt < 4; nt++)
                    acc[mt][nt] = __builtin_amdgcn_mfma_f32_16x16x32_bf16(
                        af[mt], bR[k & 1][nt], acc[mt][nt], 0, 0, 0);
        }
        // 4. stage A[k+1] (loaded ~3 iters ago) into the other LDS buffer
        if (k + 1 < 25) {
            union { short8 v8; unsigned short us[8]; } pk;
#pragma unroll
            for (int jj = 0; jj < 8; jj++) pk.us[jj] = f2bf(aR[(k + 1) % 3][jj]);
            *(short8*)(cur ? aw0 : aw1) = pk.v8;
        }
        barrier_lds();
    }

    // --- epilogue 1: bias + relu -> h1 (bf16) in LDS (overlays A buffers) ---
#pragma unroll
    for (int nt = 0; nt < 4; nt++) {
        int col = w * 64 + nt * 16 + lm;
        float bias = b1[col];
#pragma unroll
        for (int mt = 0; mt < 4; mt++) {
            f32x4 a = acc[mt][nt];
#pragma unroll
            for (int r = 0; r < 4; r++) {
                float hv = fmaxf(a[r] + bias, 0.f);
                sm.H1[(mt * 16 + lq * 4 + r) * 264 + col] = f2bf(hv);
            }
        }
    }
    __syncthreads();

    // --- layer 2: wave w does i-rows w*16..w*16+15; K=256 via 8 MFMAs ---
    f32x4 acc2 = (f32x4){0.f, 0.f, 0.f, 0.f};
#pragma unroll
    for (int kk = 0; kk < 8; kk++) {
        int kb = kk * 32 + lq * 8;
        short8 a2 = *(const short8*)(sm.H1 + (w * 16 + lm) * 264 + kb);
        short8 b2f = *(const short8*)(W2bf + lm * NH1 + kb);
        acc2 = __builtin_amdgcn_mfma_f32_16x16x32_bf16(a2, b2f, acc2, 0, 0, 0);
    }
    float b2v = b2[lm];
    float w3v = W3[lm];
    float p[4];
#pragma unroll
    for (int r = 0; r < 4; r++) p[r] = fmaxf(acc2[r] + b2v, 0.f) * w3v;
#pragma unroll
    for (int m = 1; m < 16; m <<= 1)
#pragma unroll
        for (int r = 0; r < 4; r++) p[r] += __shfl_xor(p[r], m);
    if (lm == 0) {
        float b3v = b3[0];
#pragma unroll
        for (int r = 0; r < 4; r++) {
            int gi = i0 + w * 16 + lq * 4 + r;
            if (gi < NI) fc[b * NIP + gi] = f2bf(p[r] + b3v);
        }
    }
}

// ----------------------------------------------------------------- head ----
// head1: k-split partial GEMV. Block (ks, b): psum over 128 k-values.
__global__ __launch_bounds__(256)
void head1_kernel(const unsigned short* __restrict__ fc,
                  const unsigned short* __restrict__ WpT,
                  float* __restrict__ pbuf) {
    __shared__ float fcs[128];
    const int tid = threadIdx.x;
    const int ks = blockIdx.x;    // 0..7
    const int b  = blockIdx.y;
    if (tid < 128) fcs[tid] = bf2f(fc[b * NIP + ks * 128 + tid]);
    __syncthreads();
    float acc = 0.f;
    const unsigned short* wp = WpT + (ks * 128) * NPH + tid;
#pragma unroll 8
    for (int k = 0; k < 128; k++) acc = fmaf(fcs[k], bf2f(wp[k * NPH]), acc);
    pbuf[(b * 8 + ks) * NPH + tid] = acc;
}

// head2: sum partials, relu+bp, dot with Wv.
__global__ __launch_bounds__(256)
void head2_kernel(const float* __restrict__ pbuf, const float* __restrict__ bp,
                  const float* __restrict__ Wv, const float* __restrict__ bv,
                  float* __restrict__ out) {
    __shared__ float red[4];
    const int tid = threadIdx.x;
    const int b = blockIdx.x;
    float y = bp[tid];
#pragma unroll
    for (int ks = 0; ks < 8; ks++) y += pbuf[(b * 8 + ks) * NPH + tid];
    y = fmaxf(y, 0.f);
    float pv = y * Wv[tid];
#pragma unroll
    for (int m = 1; m < 64; m <<= 1) pv += __shfl_xor(pv, m);
    if ((tid & 63) == 0) red[tid >> 6] = pv;
    __syncthreads();
    if (tid == 0) out[b] = red[0] + red[1] + red[2] + red[3] + bv[0];
}

// --------------------------------------------------------------- launch ----
extern "C" void kernel_launch(void* const* d_in, const int* in_sizes, int n_in,
                              void* d_out, int out_size, void* d_ws, size_t ws_size,
                              hipStream_t stream) {
    const float* state = (const float*)d_in[0];
    const float* W1 = (const float*)d_in[1];
    const float* b1 = (const float*)d_in[2];
    const float* W2 = (const float*)d_in[3];
    const float* b2 = (const float*)d_in[4];
    const float* W3 = (const float*)d_in[5];
    const float* b3 = (const float*)d_in[6];
    const float* Wp = (const float*)d_in[7];
    const float* bp = (const float*)d_in[8];
    const float* Wv = (const float*)d_in[9];
    const float* bv = (const float*)d_in[10];
    float* out = (float*)d_out;

    char* ws = (char*)d_ws;
    unsigned short* W1bf = (unsigned short*)ws;               //   409,600 B
    unsigned short* W2bf = (unsigned short*)(ws + 409600);    //     8,192 B
    unsigned short* WpT  = (unsigned short*)(ws + 417792);    //   524,288 B
    unsigned short* fc   = (unsigned short*)(ws + 942080);    //   524,288 B
    float*          pbuf = (float*)(ws + 1466368);            // 2,097,152 B

    prep_kernel<<<200, 256, 0, stream>>>(W1, W2, W1bf, W2bf, fc);
    wpt_kernel<<<dim3(16, 4), 256, 0, stream>>>(Wp, WpT);
    sec_kernel<<<dim3(16, 256), 256, 0, stream>>>(state, W1bf, b1, W2bf, b2, W3, b3, fc);
    head1_kernel<<<dim3(8, 256), 256, 0, stream>>>(fc, WpT, pbuf);
    head2_kernel<<<NB, 256, 0, stream>>>(pbuf, bp, Wv, bv, out);
}